// Round 6
// baseline (1776.506 us; speedup 1.0000x reference)
//
#include <hip/hip_runtime.h>
#include <hip/hip_bf16.h>

// LSTM encoder, two-phase.
// Phase 1 (xg_gemm, 256 WGs x 8 t each): xg[t][b][hh][g] = emb·Wih^T + bias, bf16.
// Phase 2 (lstm_rec, 8 WGs x 1024 thr): TWO independent 4-row recurrence groups
//   per WG share one CU -> their latency chains overlap across the shared
//   barrier. i8 MFMA (mfma_i32_16x16x64), 4-row h tile (C rows 4-15 unread so
//   A rows 4-15 may be garbage), raw-i32 gate exchange + per-lane dequant
//   fused with the xg add. One LDS-only barrier per step.

namespace {

constexpr int T_LEN = 2048;
constexpr int Bsz   = 64;
constexpr int Dd    = 128;
constexpr int Hh    = 128;
constexpr int Gg    = 512;
constexpr int NT    = 512;    // phase-1 / fallback block
constexpr int XS    = 136;    // bf16 LDS row stride (phase 1 / fallback)
constexpr int TB    = 8;      // timesteps per xg_gemm WG
constexpr int NWG_R = 8;      // rec WGs (2 groups x 4 rows each)
constexpr int NT_R  = 1024;
constexpr int HS    = 192;    // i8 h row stride bytes: rows at 0/48/96/144 words -> 2-way clean

typedef __attribute__((ext_vector_type(8))) short   short8;
typedef __attribute__((ext_vector_type(4))) float   floatx4;
typedef __attribute__((ext_vector_type(4))) int     intx4;
typedef __attribute__((ext_vector_type(2))) unsigned int uintx2;

#define MFMA16(a, b, c) __builtin_amdgcn_mfma_f32_16x16x32_bf16((a), (b), (c), 0, 0, 0)

__device__ __forceinline__ float sigmoidf_(float x) {
    return __builtin_amdgcn_rcpf(1.0f + __builtin_amdgcn_exp2f(x * -1.44269504f));
}
__device__ __forceinline__ float tanhf_(float x) {
    return __builtin_fmaf(-2.0f,
        __builtin_amdgcn_rcpf(1.0f + __builtin_amdgcn_exp2f(x * 2.88539008f)), 1.0f);
}
__device__ __forceinline__ unsigned short f2bf(float f) {
    __hip_bfloat16 h = __float2bfloat16(f);  // RNE
    union { __hip_bfloat16 b; unsigned short u; } v; v.b = h; return v.u;
}
__device__ __forceinline__ float fi_(unsigned int u) {
    union { unsigned int u; float f; } v; v.u = u; return v.f;
}
__device__ __forceinline__ uintx2 f4bf(const float4 v) {
    union { unsigned short us[4]; uintx2 u2; } p;
    p.us[0] = f2bf(v.x); p.us[1] = f2bf(v.y); p.us[2] = f2bf(v.z); p.us[3] = f2bf(v.w);
    return p.u2;
}
__device__ __forceinline__ short8 ld8bf(const float* p) {
    const float4 a = *reinterpret_cast<const float4*>(p);
    const float4 b = *reinterpret_cast<const float4*>(p + 4);
    short8 s;
    s[0] = (short)f2bf(a.x); s[1] = (short)f2bf(a.y);
    s[2] = (short)f2bf(a.z); s[3] = (short)f2bf(a.w);
    s[4] = (short)f2bf(b.x); s[5] = (short)f2bf(b.y);
    s[6] = (short)f2bf(b.z); s[7] = (short)f2bf(b.w);
    return s;
}
// barrier without the compiler's vmcnt(0) drain: LDS-visibility only
__device__ __forceinline__ void lds_barrier() {
    asm volatile("s_waitcnt lgkmcnt(0)\n\ts_barrier" ::: "memory");
}

// ---------------- Phase 1: xg = emb(tok) @ Wih^T + (bih+bhh), bf16 -----------
__global__ void xg_gemm(const int*   __restrict__ tokens,
                        const float* __restrict__ emb,
                        const float* __restrict__ Wih,
                        const float* __restrict__ bih,
                        const float* __restrict__ bhh,
                        unsigned short* __restrict__ xg)  // [T][64][128][4]
{
    __shared__ unsigned short albs[2][64 * XS];

    const int t0   = blockIdx.x * TB;
    const int tid  = threadIdx.x;
    const int w    = tid >> 6;
    const int l    = tid & 63;
    const int quad = l >> 4;
    const int cl   = l & 15;
    const int b    = tid >> 3, seg = tid & 7;   // staging lanes

    // weights + bias once per WG (amortized over TB timesteps)
    short8 wf[4][4];
    float  bias[4];
#pragma unroll
    for (int q = 0; q < 4; ++q) {
        const int n = q * 128 + w * 16 + cl;
#pragma unroll
        for (int kk = 0; kk < 4; ++kk)
            wf[q][kk] = ld8bf(Wih + n * Dd + kk * 32 + quad * 8);
        bias[q] = bih[n] + bhh[n];
    }

    {   // stage t0 into buf 0
        const int tok = tokens[b * T_LEN + t0];
        const float* src = emb + (size_t)tok * Dd + seg * 16;
        *reinterpret_cast<short8*>(&albs[0][b * XS + seg * 16])     = ld8bf(src);
        *reinterpret_cast<short8*>(&albs[0][b * XS + seg * 16 + 8]) = ld8bf(src + 8);
    }
    __syncthreads();

    const int hh = w * 16 + cl;
    for (int tt = 0; tt < TB; ++tt) {
        const int cur = tt & 1, nxt = cur ^ 1;
        if (tt + 1 < TB) {   // stage next while computing current
            const int tok = tokens[b * T_LEN + t0 + tt + 1];
            const float* src = emb + (size_t)tok * Dd + seg * 16;
            *reinterpret_cast<short8*>(&albs[nxt][b * XS + seg * 16])     = ld8bf(src);
            *reinterpret_cast<short8*>(&albs[nxt][b * XS + seg * 16 + 8]) = ld8bf(src + 8);
        }

        floatx4 acc[4][4];
#pragma unroll
        for (int mt = 0; mt < 4; ++mt)
#pragma unroll
            for (int q = 0; q < 4; ++q)
                acc[mt][q] = (floatx4){0.f, 0.f, 0.f, 0.f};

#pragma unroll
        for (int kk = 0; kk < 4; ++kk) {
            short8 af[4];
#pragma unroll
            for (int mt = 0; mt < 4; ++mt)
                af[mt] = *reinterpret_cast<const short8*>(
                    &albs[cur][(mt * 16 + cl) * XS + kk * 32 + quad * 8]);
#pragma unroll
            for (int mt = 0; mt < 4; ++mt)
#pragma unroll
                for (int q = 0; q < 4; ++q)
                    acc[mt][q] = MFMA16(af[mt], wf[q][kk], acc[mt][q]);
        }

        const int t = t0 + tt;
#pragma unroll
        for (int mt = 0; mt < 4; ++mt) {
#pragma unroll
            for (int r = 0; r < 4; ++r) {
                const int m = mt * 16 + quad * 4 + r;
                union { unsigned short us[4]; uintx2 u2; } p;
#pragma unroll
                for (int g = 0; g < 4; ++g)
                    p.us[g] = f2bf(acc[mt][g][r] + bias[g]);
                *reinterpret_cast<uintx2*>(
                    xg + ((size_t)t * Bsz + m) * Gg + hh * 4) = p.u2;
            }
        }
        __syncthreads();  // staged buf visible; albs[cur] reusable
    }
}

// ---------------- Phase 2: persistent recurrence, 2 groups/WG ----------------
__global__ __launch_bounds__(NT_R, 4) void lstm_rec(
    const unsigned short* __restrict__ xg,   // [T][64][128][4] bf16
    const float* __restrict__ Whh,           // [512][128] fp32
    float*       __restrict__ out)           // [2][64][128] fp32
{
    __shared__ __align__(16) unsigned char hq[2][2][4 * HS];  // [group][buf][4 rows i8]
    __shared__ int wscr[2][8][256];                           // [group][wave] raw gates

    const int tid  = threadIdx.x;
    const int g2   = tid >> 9;        // group 0/1
    const int w    = (tid >> 6) & 7;  // wave within group
    const int l    = tid & 63;
    const int quad = l >> 4;
    const int cl   = l & 15;
    const int bbase = blockIdx.x * 8 + g2 * 4;

    const int rr = quad;              // batch row within group
    const int hh = w * 16 + cl;       // this wave's 16 hh cols

    // ---- Whh per-row i8 quantization; fragments k = kk*64 + quad*16 + j ----
    intx4 wq[4][2];
    float dq[4];
#pragma unroll
    for (int q = 0; q < 4; ++q) {
        const int n = q * 128 + w * 16 + cl;
        const float* wr = Whh + n * Hh;
        float am = 0.f;
#pragma unroll 8
        for (int k = 0; k < 128; k += 4) {
            const float4 v = *reinterpret_cast<const float4*>(wr + k);
            am = fmaxf(am, fmaxf(fmaxf(fabsf(v.x), fabsf(v.y)),
                                 fmaxf(fabsf(v.z), fabsf(v.w))));
        }
        const float swm = fmaxf(am, 1e-20f);
        dq[q] = swm * (1.0f / (127.0f * 127.0f));
        const float inv = 127.0f / swm;
#pragma unroll
        for (int kk = 0; kk < 2; ++kk) {
            int e[4];
#pragma unroll
            for (int g4 = 0; g4 < 4; ++g4) {
                const int kb = kk * 64 + quad * 16 + g4 * 4;
                const int b0 = (int)__builtin_rintf(wr[kb + 0] * inv);
                const int b1 = (int)__builtin_rintf(wr[kb + 1] * inv);
                const int b2 = (int)__builtin_rintf(wr[kb + 2] * inv);
                const int b3 = (int)__builtin_rintf(wr[kb + 3] * inv);
                e[g4] = (b0 & 0xff) | ((b1 & 0xff) << 8) |
                        ((b2 & 0xff) << 16) | ((b3 & 0xff) << 24);
            }
            wq[q][kk] = (intx4){e[0], e[1], e[2], e[3]};
        }
    }

    // zero both groups' h tiles (h0 = 0)
    for (int i = tid; i < 2 * 2 * 4 * HS; i += NT_R)
        (&hq[0][0][0])[i] = 0;

    // xg chunked prefetch: 8 steps per refill
    const unsigned short* xptr = xg + (size_t)(bbase + rr) * Gg + hh * 4;
    const size_t xstride = (size_t)Bsz * Gg;
    uintx2 xc[8], xcn[8];
#pragma unroll
    for (int u = 0; u < 8; ++u)
        xc[u] = *reinterpret_cast<const uintx2*>(xptr + (size_t)u * xstride);

    __syncthreads();  // zeros visible

    float c_state = 0.0f;
    float h_last  = 0.0f;

    for (int g = 0; g < T_LEN / 8; ++g) {
#pragma unroll
        for (int s = 0; s < 8; ++s) {
            const int cur = s & 1, nxt = cur ^ 1;

            if (s == 0) {   // refill next group's xg; never drained at barriers
                size_t tn = (size_t)(g + 1) * 8;
                if (tn >= (size_t)T_LEN) tn = 0;
#pragma unroll
                for (int u = 0; u < 8; ++u)
                    xcn[u] = *reinterpret_cast<const uintx2*>(
                        xptr + (tn + u) * xstride);
            }

            // h A-fragments; rows 4-15 of the MFMA A-tile are don't-care
            // (C rows 4-15 unread), so every lane reads row (cl&3) -> broadcast.
            const unsigned char* hb = &hq[g2][cur][0];
            const intx4 hf0 = *reinterpret_cast<const intx4*>(
                hb + (cl & 3) * HS + quad * 16);
            const intx4 hf1 = *reinterpret_cast<const intx4*>(
                hb + (cl & 3) * HS + quad * 16 + 64);

            intx4 acc[4];
#pragma unroll
            for (int q = 0; q < 4; ++q)
                acc[q] = __builtin_amdgcn_mfma_i32_16x16x64_i8(
                    hf0, wq[q][0], (intx4){0, 0, 0, 0}, 0, 0, 0);
#pragma unroll
            for (int q = 0; q < 4; ++q)
                acc[q] = __builtin_amdgcn_mfma_i32_16x16x64_i8(
                    hf1, wq[q][1], acc[q], 0, 0, 0);

            // raw-i32 gate exchange through per-wave scratch (same-wave DS order)
            if (quad == 0) {
#pragma unroll
                for (int r = 0; r < 4; ++r)
                    *reinterpret_cast<intx4*>(&wscr[g2][w][(r * 16 + cl) * 4]) =
                        (intx4){acc[0][r], acc[1][r], acc[2][r], acc[3][r]};
            }
            __builtin_amdgcn_wave_barrier();

            const intx4 gi = *reinterpret_cast<const intx4*>(&wscr[g2][w][l * 4]);
            const uintx2 xv = xc[s];
            const float iv = (float)gi[0] * dq[0] + fi_(xv.x << 16);
            const float fv = (float)gi[1] * dq[1] + fi_(xv.x & 0xffff0000u);
            const float gv = (float)gi[2] * dq[2] + fi_(xv.y << 16);
            const float ov = (float)gi[3] * dq[3] + fi_(xv.y & 0xffff0000u);
            const float si = sigmoidf_(iv);
            const float sf = sigmoidf_(fv);
            const float so = sigmoidf_(ov);
            const float tg = tanhf_(gv);
            c_state = sf * c_state + si * tg;
            h_last  = so * tanhf_(c_state);
            hq[g2][nxt][rr * HS + hh] =
                (unsigned char)(((int)__builtin_rintf(h_last * 127.0f)) & 0xff);

            if (s == 7) {
#pragma unroll
                for (int u = 0; u < 8; ++u) xc[u] = xcn[u];
            }
            lds_barrier();  // LDS-only: h(t+1) visible, xg loads stay in flight
        }
    }

    const int ob = (bbase + rr) * Hh + hh;
    out[ob]            = h_last;
    out[Bsz * Hh + ob] = c_state;
}

// ---------------- Fallback (R2 working kernel) if ws too small ---------------
__global__ __launch_bounds__(NT, 2) void lstm_fused_fb(
    const int*   __restrict__ tokens,
    const float* __restrict__ emb,
    const float* __restrict__ Wih,
    const float* __restrict__ Whh,
    const float* __restrict__ bih,
    const float* __restrict__ bhh,
    float*       __restrict__ out)
{
    __shared__ unsigned short xbuf[2][16 * XS];
    __shared__ unsigned short hbuf[2][16 * XS];
    __shared__ float scratch[4 * Gg];

    const int tid  = threadIdx.x;
    const int w    = tid >> 6;
    const int l    = tid & 63;
    const int quad = l >> 4;
    const int cl   = l & 15;
    const int bbase = blockIdx.x * 4;
    const int rr = tid >> 7;
    const int hh = tid & 127;

    short8 wih[4][4], whh[4][4];
    float  bias[4];
#pragma unroll
    for (int q = 0; q < 4; ++q) {
        const int n = q * 128 + w * 16 + cl;
#pragma unroll
        for (int kk = 0; kk < 4; ++kk) {
            const int k0 = kk * 32 + quad * 8;
            wih[q][kk] = ld8bf(Wih + n * Dd + k0);
            whh[q][kk] = ld8bf(Whh + n * Hh + k0);
        }
        bias[q] = bih[n] + bhh[n];
    }

    for (int i = tid; i < 16 * XS; i += NT) {
        xbuf[0][i] = 0; xbuf[1][i] = 0; hbuf[0][i] = 0; hbuf[1][i] = 0;
    }

    const bool gact = (tid < 128);
    const int  gr = tid >> 5;
    const int  gp = tid & 31;
    float4 gdataf = {0.f, 0.f, 0.f, 0.f};
    if (gact) {
        const int tok = tokens[(bbase + gr) * T_LEN + 0];
        gdataf = *reinterpret_cast<const float4*>(emb + (size_t)tok * Dd + gp * 4);
    }
    __syncthreads();
    if (gact) *reinterpret_cast<uintx2*>(&xbuf[0][gr * XS + gp * 4]) = f4bf(gdataf);
    if (gact) {
        const int tok = tokens[(bbase + gr) * T_LEN + 1];
        gdataf = *reinterpret_cast<const float4*>(emb + (size_t)tok * Dd + gp * 4);
    }
    __syncthreads();

    const int afrag_el = cl * XS + quad * 8;

    floatx4 acc[4];
#pragma unroll
    for (int q = 0; q < 4; ++q) acc[q] = (floatx4){bias[q], bias[q], bias[q], bias[q]};
    {
        short8 xf[4];
#pragma unroll
        for (int kk = 0; kk < 4; ++kk)
            xf[kk] = *reinterpret_cast<const short8*>(&xbuf[0][afrag_el + kk * 32]);
#pragma unroll
        for (int kk = 0; kk < 4; ++kk)
#pragma unroll
            for (int q = 0; q < 4; ++q)
                acc[q] = MFMA16(xf[kk], wih[q][kk], acc[q]);
    }

    float c_state = 0.0f, h_last = 0.0f;

    for (int t = 0; t < T_LEN; ++t) {
        const int cur = t & 1, nxt = cur ^ 1;
        short8 hf[4];
#pragma unroll
        for (int kk = 0; kk < 4; ++kk)
            hf[kk] = *reinterpret_cast<const short8*>(&hbuf[cur][afrag_el + kk * 32]);
        if (gact && (t + 1 < T_LEN))
            *reinterpret_cast<uintx2*>(&xbuf[nxt][gr * XS + gp * 4]) = f4bf(gdataf);
        if (gact && (t + 2 < T_LEN)) {
            const int tok = tokens[(bbase + gr) * T_LEN + (t + 2)];
            gdataf = *reinterpret_cast<const float4*>(emb + (size_t)tok * Dd + gp * 4);
        }
#pragma unroll
        for (int kk = 0; kk < 4; ++kk)
#pragma unroll
            for (int q = 0; q < 4; ++q)
                acc[q] = MFMA16(hf[kk], whh[q][kk], acc[q]);
        if (quad == 0) {
#pragma unroll
            for (int q = 0; q < 4; ++q) {
                const int n = q * 128 + w * 16 + cl;
#pragma unroll
                for (int r = 0; r < 4; ++r)
                    scratch[r * Gg + n] = acc[q][r];
            }
        }
        __syncthreads();
#pragma unroll
        for (int q = 0; q < 4; ++q) acc[q] = (floatx4){bias[q], bias[q], bias[q], bias[q]};
        if (t + 1 < T_LEN) {
            short8 xf[4];
#pragma unroll
            for (int kk = 0; kk < 4; ++kk)
                xf[kk] = *reinterpret_cast<const short8*>(&xbuf[nxt][afrag_el + kk * 32]);
#pragma unroll
            for (int kk = 0; kk < 4; ++kk)
#pragma unroll
                for (int q = 0; q < 4; ++q)
                    acc[q] = MFMA16(xf[kk], wih[q][kk], acc[q]);
        }
        {
            const float iv = scratch[rr * Gg + hh];
            const float fv = scratch[rr * Gg + 128 + hh];
            const float gv = scratch[rr * Gg + 256 + hh];
            const float ov = scratch[rr * Gg + 384 + hh];
            const float si = sigmoidf_(iv);
            const float sf = sigmoidf_(fv);
            const float so = sigmoidf_(ov);
            const float tg = tanhf_(gv);
            c_state = sf * c_state + si * tg;
            h_last  = so * tanhf_(c_state);
            hbuf[nxt][rr * XS + hh] = f2bf(h_last);
        }
        __syncthreads();
    }

    const int ob = (bbase + rr) * Hh + hh;
    out[ob]            = h_last;
    out[Bsz * Hh + ob] = c_state;
}

}  // namespace

extern "C" void kernel_launch(void* const* d_in, const int* in_sizes, int n_in,
                              void* d_out, int out_size, void* d_ws, size_t ws_size,
                              hipStream_t stream) {
    (void)in_sizes; (void)n_in; (void)out_size;
    const int*   tokens = (const int*)d_in[0];
    const float* emb    = (const float*)d_in[1];
    const float* Wih    = (const float*)d_in[2];
    const float* Whh    = (const float*)d_in[3];
    const float* bih    = (const float*)d_in[4];
    const float* bhh    = (const float*)d_in[5];

    const size_t need = (size_t)T_LEN * Bsz * Gg * sizeof(unsigned short);  // 134 MB
    if (ws_size >= need) {
        unsigned short* xg = (unsigned short*)d_ws;
        xg_gemm<<<T_LEN / TB, NT, 0, stream>>>(tokens, emb, Wih, bih, bhh, xg);
        lstm_rec<<<NWG_R, NT_R, 0, stream>>>(xg, Whh, (float*)d_out);
    } else {
        lstm_fused_fb<<<NWG_R * 2, NT, 0, stream>>>(tokens, emb, Wih, Whh, bih, bhh,
                                                    (float*)d_out);
    }
}

// Round 7
// 1067.426 us; speedup vs baseline: 1.6643x; 1.6643x over previous
//
#include <hip/hip_runtime.h>
#include <hip/hip_bf16.h>

// LSTM encoder, two-phase.
// Phase 1 (xg_gemm, 256 WGs x 8 t): xg[t][b][hh][g] = emb·Wih^T + bias, bf16.
// Phase 2 (lstm_rec_dot, 64 WGs x 128 thr = 2 waves = ONE batch row):
//   lane = one hidden column. Whh (4 rows x 128) as i8 in 128 VGPRs/lane,
//   h(t) replicated in 32 dwords/lane. Per step: 128 v_dot4_i32_i8 +
//   per-lane dequant + xg add + full LSTM cell in-lane + 1-byte i8 h publish
//   to a 128-B LDS ping-pong + ONE lgkmcnt-only barrier + 8 broadcast
//   ds_read_b128. No MFMA, no gate exchange, ~10 DS ops/step.

namespace {

constexpr int T_LEN = 2048;
constexpr int Bsz   = 64;
constexpr int Dd    = 128;
constexpr int Hh    = 128;
constexpr int Gg    = 512;
constexpr int NT    = 512;    // phase-1 / fallback block
constexpr int XS    = 136;    // bf16 LDS row stride (phase 1 / fallback)
constexpr int TB    = 8;      // timesteps per xg_gemm WG

typedef __attribute__((ext_vector_type(8))) short   short8;
typedef __attribute__((ext_vector_type(4))) float   floatx4;
typedef __attribute__((ext_vector_type(4))) int     intx4;
typedef __attribute__((ext_vector_type(2))) unsigned int uintx2;

#define MFMA16(a, b, c) __builtin_amdgcn_mfma_f32_16x16x32_bf16((a), (b), (c), 0, 0, 0)

#if __has_builtin(__builtin_amdgcn_sdot4)
__device__ __forceinline__ int dot4i8(int a, int b, int c) {
    return __builtin_amdgcn_sdot4(a, b, c, false);
}
#else
__device__ __forceinline__ int dot4i8(int a, int b, int c) {
#pragma unroll
    for (int j = 0; j < 4; ++j)
        c += ((a << (24 - 8 * j)) >> 24) * ((b << (24 - 8 * j)) >> 24);
    return c;
}
#endif

__device__ __forceinline__ float sigmoidf_(float x) {
    return __builtin_amdgcn_rcpf(1.0f + __builtin_amdgcn_exp2f(x * -1.44269504f));
}
__device__ __forceinline__ float tanhf_(float x) {
    return __builtin_fmaf(-2.0f,
        __builtin_amdgcn_rcpf(1.0f + __builtin_amdgcn_exp2f(x * 2.88539008f)), 1.0f);
}
__device__ __forceinline__ unsigned short f2bf(float f) {
    __hip_bfloat16 h = __float2bfloat16(f);  // RNE
    union { __hip_bfloat16 b; unsigned short u; } v; v.b = h; return v.u;
}
__device__ __forceinline__ float fi_(unsigned int u) {
    union { unsigned int u; float f; } v; v.u = u; return v.f;
}
__device__ __forceinline__ uintx2 f4bf(const float4 v) {
    union { unsigned short us[4]; uintx2 u2; } p;
    p.us[0] = f2bf(v.x); p.us[1] = f2bf(v.y); p.us[2] = f2bf(v.z); p.us[3] = f2bf(v.w);
    return p.u2;
}
__device__ __forceinline__ short8 ld8bf(const float* p) {
    const float4 a = *reinterpret_cast<const float4*>(p);
    const float4 b = *reinterpret_cast<const float4*>(p + 4);
    short8 s;
    s[0] = (short)f2bf(a.x); s[1] = (short)f2bf(a.y);
    s[2] = (short)f2bf(a.z); s[3] = (short)f2bf(a.w);
    s[4] = (short)f2bf(b.x); s[5] = (short)f2bf(b.y);
    s[6] = (short)f2bf(b.z); s[7] = (short)f2bf(b.w);
    return s;
}
// barrier without the compiler's vmcnt(0) drain: LDS-visibility only
__device__ __forceinline__ void lds_barrier() {
    asm volatile("s_waitcnt lgkmcnt(0)\n\ts_barrier" ::: "memory");
}

// ---------------- Phase 1: xg = emb(tok) @ Wih^T + (bih+bhh), bf16 -----------
__global__ void xg_gemm(const int*   __restrict__ tokens,
                        const float* __restrict__ emb,
                        const float* __restrict__ Wih,
                        const float* __restrict__ bih,
                        const float* __restrict__ bhh,
                        unsigned short* __restrict__ xg)  // [T][64][128][4]
{
    __shared__ unsigned short albs[2][64 * XS];

    const int t0   = blockIdx.x * TB;
    const int tid  = threadIdx.x;
    const int w    = tid >> 6;
    const int l    = tid & 63;
    const int quad = l >> 4;
    const int cl   = l & 15;
    const int b    = tid >> 3, seg = tid & 7;   // staging lanes

    short8 wf[4][4];
    float  bias[4];
#pragma unroll
    for (int q = 0; q < 4; ++q) {
        const int n = q * 128 + w * 16 + cl;
#pragma unroll
        for (int kk = 0; kk < 4; ++kk)
            wf[q][kk] = ld8bf(Wih + n * Dd + kk * 32 + quad * 8);
        bias[q] = bih[n] + bhh[n];
    }

    {   // stage t0 into buf 0
        const int tok = tokens[b * T_LEN + t0];
        const float* src = emb + (size_t)tok * Dd + seg * 16;
        *reinterpret_cast<short8*>(&albs[0][b * XS + seg * 16])     = ld8bf(src);
        *reinterpret_cast<short8*>(&albs[0][b * XS + seg * 16 + 8]) = ld8bf(src + 8);
    }
    __syncthreads();

    const int hh = w * 16 + cl;
    for (int tt = 0; tt < TB; ++tt) {
        const int cur = tt & 1, nxt = cur ^ 1;
        if (tt + 1 < TB) {   // stage next while computing current
            const int tok = tokens[b * T_LEN + t0 + tt + 1];
            const float* src = emb + (size_t)tok * Dd + seg * 16;
            *reinterpret_cast<short8*>(&albs[nxt][b * XS + seg * 16])     = ld8bf(src);
            *reinterpret_cast<short8*>(&albs[nxt][b * XS + seg * 16 + 8]) = ld8bf(src + 8);
        }

        floatx4 acc[4][4];
#pragma unroll
        for (int mt = 0; mt < 4; ++mt)
#pragma unroll
            for (int q = 0; q < 4; ++q)
                acc[mt][q] = (floatx4){0.f, 0.f, 0.f, 0.f};

#pragma unroll
        for (int kk = 0; kk < 4; ++kk) {
            short8 af[4];
#pragma unroll
            for (int mt = 0; mt < 4; ++mt)
                af[mt] = *reinterpret_cast<const short8*>(
                    &albs[cur][(mt * 16 + cl) * XS + kk * 32 + quad * 8]);
#pragma unroll
            for (int mt = 0; mt < 4; ++mt)
#pragma unroll
                for (int q = 0; q < 4; ++q)
                    acc[mt][q] = MFMA16(af[mt], wf[q][kk], acc[mt][q]);
        }

        const int t = t0 + tt;
#pragma unroll
        for (int mt = 0; mt < 4; ++mt) {
#pragma unroll
            for (int r = 0; r < 4; ++r) {
                const int m = mt * 16 + quad * 4 + r;
                union { unsigned short us[4]; uintx2 u2; } p;
#pragma unroll
                for (int g = 0; g < 4; ++g)
                    p.us[g] = f2bf(acc[mt][g][r] + bias[g]);
                *reinterpret_cast<uintx2*>(
                    xg + ((size_t)t * Bsz + m) * Gg + hh * 4) = p.u2;
            }
        }
        __syncthreads();
    }
}

// ---------------- Phase 2: per-row dot4 recurrence, 2 waves/WG ---------------
__global__ __launch_bounds__(128) void lstm_rec_dot(
    const unsigned short* __restrict__ xg,   // [T][64][128][4] bf16
    const float* __restrict__ Whh,           // [512][128] fp32
    float*       __restrict__ out)           // [2][64][128] fp32
{
    __shared__ __align__(16) signed char hbuf[2][128];   // h(t) i8, ping-pong

    const int hh = threadIdx.x;      // 0..127: this lane's hidden column
    const int b  = blockIdx.x;       // batch row

    // ---- Whh rows {q*128+hh} -> i8, per-row scale (two-pass) ----
    int   wq[4][32];
    float dq[4];
#pragma unroll
    for (int q = 0; q < 4; ++q) {
        const float* wr = Whh + (size_t)(q * 128 + hh) * Hh;
        float am = 0.f;
#pragma unroll 8
        for (int k = 0; k < 128; k += 4) {
            const float4 v = *reinterpret_cast<const float4*>(wr + k);
            am = fmaxf(am, fmaxf(fmaxf(fabsf(v.x), fabsf(v.y)),
                                 fmaxf(fabsf(v.z), fabsf(v.w))));
        }
        const float swm = fmaxf(am, 1e-20f);
        dq[q] = swm * (1.0f / (127.0f * 127.0f));
        const float inv = 127.0f / swm;
#pragma unroll
        for (int d = 0; d < 32; ++d) {
            const float4 v = *reinterpret_cast<const float4*>(wr + d * 4);
            const int b0 = (int)__builtin_rintf(v.x * inv);
            const int b1 = (int)__builtin_rintf(v.y * inv);
            const int b2 = (int)__builtin_rintf(v.z * inv);
            const int b3 = (int)__builtin_rintf(v.w * inv);
            wq[q][d] = (b0 & 0xff) | ((b1 & 0xff) << 8) |
                       ((b2 & 0xff) << 16) | ((b3 & 0xff) << 24);
        }
    }

    // h(0) = 0 replicated
    intx4 hv[8];
#pragma unroll
    for (int j = 0; j < 8; ++j) hv[j] = (intx4){0, 0, 0, 0};

    // xg prefetch: lane reads its 4 gates (8 B) per step, 8-step chunks
    const unsigned short* xptr = xg + (size_t)b * Gg + hh * 4;
    const size_t xstride = (size_t)Bsz * Gg;
    uintx2 xc[8], xcn[8];
#pragma unroll
    for (int u = 0; u < 8; ++u)
        xc[u] = *reinterpret_cast<const uintx2*>(xptr + (size_t)u * xstride);

    float c_state = 0.0f;
    float h_last  = 0.0f;

    for (int g = 0; g < T_LEN / 8; ++g) {
#pragma unroll
        for (int s = 0; s < 8; ++s) {
            if (s == 0) {   // refill next chunk; never drained (lds_barrier only)
                size_t tn = (size_t)(g + 1) * 8;
                if (tn >= (size_t)T_LEN) tn = 0;
#pragma unroll
                for (int u = 0; u < 8; ++u)
                    xcn[u] = *reinterpret_cast<const uintx2*>(
                        xptr + (tn + u) * xstride);
            }

            // gates = Whh_row · h  (i8 dot4, exact i32 accumulate)
            int ai = 0, af = 0, ag = 0, ao = 0;
#pragma unroll
            for (int j = 0; j < 8; ++j) {
#pragma unroll
                for (int e = 0; e < 4; ++e) {
                    const int hd = hv[j][e];
                    const int d  = j * 4 + e;
                    ai = dot4i8(wq[0][d], hd, ai);
                    af = dot4i8(wq[1][d], hd, af);
                    ag = dot4i8(wq[2][d], hd, ag);
                    ao = dot4i8(wq[3][d], hd, ao);
                }
            }

            const uintx2 xv = xc[s];
            const float iv = (float)ai * dq[0] + fi_(xv.x << 16);
            const float fv = (float)af * dq[1] + fi_(xv.x & 0xffff0000u);
            const float gv = (float)ag * dq[2] + fi_(xv.y << 16);
            const float ov = (float)ao * dq[3] + fi_(xv.y & 0xffff0000u);
            const float si = sigmoidf_(iv);
            const float sf = sigmoidf_(fv);
            const float so = sigmoidf_(ov);
            const float tg = tanhf_(gv);
            c_state = sf * c_state + si * tg;
            h_last  = so * tanhf_(c_state);

            // publish h(t+1) as i8, refresh the replicated copy
            const int nxt = ~(g * 8 + s) & 1;  // buffer for t+1: (t+1)&1
            hbuf[nxt][hh] =
                (signed char)((int)__builtin_rintf(h_last * 127.0f));
            if (s == 7) {
#pragma unroll
                for (int u = 0; u < 8; ++u) xc[u] = xcn[u];
            }
            lds_barrier();  // lgkmcnt-only: h bytes visible, vmem stays in flight
#pragma unroll
            for (int j = 0; j < 8; ++j)
                hv[j] = *reinterpret_cast<const intx4*>(&hbuf[nxt][j * 16]);
        }
    }

    const int ob = b * Hh + hh;
    out[ob]            = h_last;
    out[Bsz * Hh + ob] = c_state;
}

// ---------------- Fallback (R2 working kernel) if ws too small ---------------
__global__ __launch_bounds__(NT, 2) void lstm_fused_fb(
    const int*   __restrict__ tokens,
    const float* __restrict__ emb,
    const float* __restrict__ Wih,
    const float* __restrict__ Whh,
    const float* __restrict__ bih,
    const float* __restrict__ bhh,
    float*       __restrict__ out)
{
    __shared__ unsigned short xbuf[2][16 * XS];
    __shared__ unsigned short hbuf2[2][16 * XS];
    __shared__ float scratch[4 * Gg];

    const int tid  = threadIdx.x;
    const int w    = tid >> 6;
    const int l    = tid & 63;
    const int quad = l >> 4;
    const int cl   = l & 15;
    const int bbase = blockIdx.x * 4;
    const int rr = tid >> 7;
    const int hh = tid & 127;

    short8 wih[4][4], whh[4][4];
    float  bias[4];
#pragma unroll
    for (int q = 0; q < 4; ++q) {
        const int n = q * 128 + w * 16 + cl;
#pragma unroll
        for (int kk = 0; kk < 4; ++kk) {
            const int k0 = kk * 32 + quad * 8;
            wih[q][kk] = ld8bf(Wih + n * Dd + k0);
            whh[q][kk] = ld8bf(Whh + n * Hh + k0);
        }
        bias[q] = bih[n] + bhh[n];
    }

    for (int i = tid; i < 16 * XS; i += NT) {
        xbuf[0][i] = 0; xbuf[1][i] = 0; hbuf2[0][i] = 0; hbuf2[1][i] = 0;
    }

    const bool gact = (tid < 128);
    const int  gr = tid >> 5;
    const int  gp = tid & 31;
    float4 gdataf = {0.f, 0.f, 0.f, 0.f};
    if (gact) {
        const int tok = tokens[(bbase + gr) * T_LEN + 0];
        gdataf = *reinterpret_cast<const float4*>(emb + (size_t)tok * Dd + gp * 4);
    }
    __syncthreads();
    if (gact) *reinterpret_cast<uintx2*>(&xbuf[0][gr * XS + gp * 4]) = f4bf(gdataf);
    if (gact) {
        const int tok = tokens[(bbase + gr) * T_LEN + 1];
        gdataf = *reinterpret_cast<const float4*>(emb + (size_t)tok * Dd + gp * 4);
    }
    __syncthreads();

    const int afrag_el = cl * XS + quad * 8;

    floatx4 acc[4];
#pragma unroll
    for (int q = 0; q < 4; ++q) acc[q] = (floatx4){bias[q], bias[q], bias[q], bias[q]};
    {
        short8 xf[4];
#pragma unroll
        for (int kk = 0; kk < 4; ++kk)
            xf[kk] = *reinterpret_cast<const short8*>(&xbuf[0][afrag_el + kk * 32]);
#pragma unroll
        for (int kk = 0; kk < 4; ++kk)
#pragma unroll
            for (int q = 0; q < 4; ++q)
                acc[q] = MFMA16(xf[kk], wih[q][kk], acc[q]);
    }

    float c_state = 0.0f, h_last = 0.0f;

    for (int t = 0; t < T_LEN; ++t) {
        const int cur = t & 1, nxt = cur ^ 1;
        short8 hf[4];
#pragma unroll
        for (int kk = 0; kk < 4; ++kk)
            hf[kk] = *reinterpret_cast<const short8*>(&hbuf2[cur][afrag_el + kk * 32]);
        if (gact && (t + 1 < T_LEN))
            *reinterpret_cast<uintx2*>(&xbuf[nxt][gr * XS + gp * 4]) = f4bf(gdataf);
        if (gact && (t + 2 < T_LEN)) {
            const int tok = tokens[(bbase + gr) * T_LEN + (t + 2)];
            gdataf = *reinterpret_cast<const float4*>(emb + (size_t)tok * Dd + gp * 4);
        }
#pragma unroll
        for (int kk = 0; kk < 4; ++kk)
#pragma unroll
            for (int q = 0; q < 4; ++q)
                acc[q] = MFMA16(hf[kk], whh[q][kk], acc[q]);
        if (quad == 0) {
#pragma unroll
            for (int q = 0; q < 4; ++q) {
                const int n = q * 128 + w * 16 + cl;
#pragma unroll
                for (int r = 0; r < 4; ++r)
                    scratch[r * Gg + n] = acc[q][r];
            }
        }
        __syncthreads();
#pragma unroll
        for (int q = 0; q < 4; ++q) acc[q] = (floatx4){bias[q], bias[q], bias[q], bias[q]};
        if (t + 1 < T_LEN) {
            short8 xf[4];
#pragma unroll
            for (int kk = 0; kk < 4; ++kk)
                xf[kk] = *reinterpret_cast<const short8*>(&xbuf[nxt][afrag_el + kk * 32]);
#pragma unroll
            for (int kk = 0; kk < 4; ++kk)
#pragma unroll
                for (int q = 0; q < 4; ++q)
                    acc[q] = MFMA16(xf[kk], wih[q][kk], acc[q]);
        }
        {
            const float iv = scratch[rr * Gg + hh];
            const float fv = scratch[rr * Gg + 128 + hh];
            const float gv = scratch[rr * Gg + 256 + hh];
            const float ov = scratch[rr * Gg + 384 + hh];
            const float si = sigmoidf_(iv);
            const float sf = sigmoidf_(fv);
            const float so = sigmoidf_(ov);
            const float tg = tanhf_(gv);
            c_state = sf * c_state + si * tg;
            h_last  = so * tanhf_(c_state);
            hbuf2[nxt][rr * XS + hh] = f2bf(h_last);
        }
        __syncthreads();
    }

    const int ob = (bbase + rr) * Hh + hh;
    out[ob]            = h_last;
    out[Bsz * Hh + ob] = c_state;
}

}  // namespace

extern "C" void kernel_launch(void* const* d_in, const int* in_sizes, int n_in,
                              void* d_out, int out_size, void* d_ws, size_t ws_size,
                              hipStream_t stream) {
    (void)in_sizes; (void)n_in; (void)out_size;
    const int*   tokens = (const int*)d_in[0];
    const float* emb    = (const float*)d_in[1];
    const float* Wih    = (const float*)d_in[2];
    const float* Whh    = (const float*)d_in[3];
    const float* bih    = (const float*)d_in[4];
    const float* bhh    = (const float*)d_in[5];

    const size_t need = (size_t)T_LEN * Bsz * Gg * sizeof(unsigned short);  // 134 MB
    if (ws_size >= need) {
        unsigned short* xg = (unsigned short*)d_ws;
        xg_gemm<<<T_LEN / TB, NT, 0, stream>>>(tokens, emb, Wih, bih, bhh, xg);
        lstm_rec_dot<<<Bsz, 128, 0, stream>>>(xg, Whh, (float*)d_out);
    } else {
        lstm_fused_fb<<<16, NT, 0, stream>>>(tokens, emb, Wih, Whh, bih, bhh,
                                             (float*)d_out);
    }
}